// Round 2
// baseline (392.297 us; speedup 1.0000x reference)
//
#include <hip/hip_runtime.h>

typedef unsigned short u16;
typedef unsigned int u32;
typedef __attribute__((ext_vector_type(8))) short short8;
typedef __attribute__((ext_vector_type(4))) short short4_t;
typedef __attribute__((ext_vector_type(4))) float f32x4;

__device__ __forceinline__ float bf2f(u16 u){ return __uint_as_float(((u32)u)<<16); }
__device__ __forceinline__ u16 f2bf(float f){ u32 x = __float_as_uint(f); return (u16)((x + 0x7FFFu + ((x>>16)&1u)) >> 16); }

// ---------------- workspace layout (bytes) ----------------
#define OFF_FLAG   ((size_t)0)
#define OFF_COUNTS ((size_t)256)
#define OFF_LISTS  ((size_t)4096)
#define OFF_XN     ((size_t)(1<<20))
#define OFF_CTXN   (OFF_XN    + (size_t)67108864)
#define OFF_WQT    (OFF_CTXN  + (size_t)4194304)
#define OFF_WKVT   (OFF_WQT   + (size_t)2097152)
#define OFF_WOUTT  (OFF_WKVT  + (size_t)2097152)
#define OFF_Q      (OFF_WOUTT + (size_t)2097152)
#define OFF_KV     (OFF_Q     + (size_t)16777216)
#define OFF_ATTN   (OFF_KV    + (size_t)4194304)
#define WS_NEEDED  (OFF_ATTN  + (size_t)16777216)

// ---------------- prep: detect int64 + zero bucket counts ----------------
__global__ void prep_kernel(const int* __restrict__ ml32, int* __restrict__ flag, int* __restrict__ counts){
  int t = threadIdx.x;
  if (t < 32) counts[t] = 0;
  __shared__ int nz;
  if (t == 0) nz = 0;
  __syncthreads();
  // if int64: odd int32 words are the (zero) high halves of values in [0,8)
  if (t < 128 && ml32[2*t+1] != 0) atomicAdd(&nz, 1);
  __syncthreads();
  if (t == 0) flag[0] = (nz == 0) ? 1 : 0;
}

// ---------------- fused LayerNorm -> bf16 ----------------
template<int D>
__global__ __launch_bounds__(256) void ln_bf16(const float* __restrict__ x, const float* __restrict__ w,
                                               const float* __restrict__ b, u16* __restrict__ out){
  constexpr int VEC = D/256;
  int row = blockIdx.x;
  const float* xr = x + (size_t)row*D;
  int tid = threadIdx.x;
  float v[VEC];
  #pragma unroll
  for (int i=0;i<VEC;i+=4){
    f32x4 f = *(const f32x4*)(xr + tid*VEC + i);
    v[i]=f[0]; v[i+1]=f[1]; v[i+2]=f[2]; v[i+3]=f[3];
  }
  float s=0.f, sq=0.f;
  #pragma unroll
  for (int i=0;i<VEC;++i){ s += v[i]; sq += v[i]*v[i]; }
  #pragma unroll
  for (int off=32;off;off>>=1){ s += __shfl_xor(s,off,64); sq += __shfl_xor(sq,off,64); }
  __shared__ float red[8];
  int lane = tid&63, wid = tid>>6;
  if (lane==0){ red[wid]=s; red[4+wid]=sq; }
  __syncthreads();
  s  = red[0]+red[1]+red[2]+red[3];
  sq = red[4]+red[5]+red[6]+red[7];
  float mu = s/(float)D;
  float var = sq/(float)D - mu*mu;
  float rs = rsqrtf(var + 1e-5f);
  u16 o[VEC];
  #pragma unroll
  for (int i=0;i<VEC;i+=4){
    f32x4 wv = *(const f32x4*)(w + tid*VEC + i);
    f32x4 bv = *(const f32x4*)(b + tid*VEC + i);
    #pragma unroll
    for (int u=0;u<4;++u) o[i+u] = f2bf((v[i+u]-mu)*rs*wv[u] + bv[u]);
  }
  if constexpr (VEC==8) *(short8*)(out + (size_t)row*D + tid*8) = *(short8*)o;
  else                  *(short4_t*)(out + (size_t)row*D + tid*4) = *(short4_t*)o;
}

// ---------------- tiled transpose f32 [K][N] -> bf16 [N][K] ----------------
__global__ __launch_bounds__(256) void transpose_w(const float* __restrict__ in, u16* __restrict__ out, int K, int N){
  __shared__ float t[32][33];
  int tx = threadIdx.x, ty = threadIdx.y;
  int n0 = blockIdx.x*32, k0 = blockIdx.y*32;
  #pragma unroll
  for (int r=0;r<32;r+=8) t[ty+r][tx] = in[(size_t)(k0+ty+r)*N + n0+tx];
  __syncthreads();
  #pragma unroll
  for (int r=0;r<32;r+=8) out[(size_t)(n0+ty+r)*K + k0+tx] = f2bf(t[tx][ty+r]);
}

// ---------------- bf16 GEMM: C[M,N] = A[M,K] * B^T  (B stored [N][K]) ----------------
// m97 structure: 128x128 tile, BK=32, 4 waves (2x2 of 64x64), 16x16x32 MFMA,
// global_load_lds width-16 staging, double-buffered LDS, 1 barrier/K-step.
template<int OUT_BF16>
__global__ __launch_bounds__(256) void gemm_bt(const u16* __restrict__ A, const u16* __restrict__ B,
                                               void* __restrict__ Cv, int M, int N, int K){
  __shared__ __align__(16) u16 lds[2][2][128*32];
  int tid = threadIdx.x, lane = tid&63, wid = tid>>6;
  int nbn = N>>7;
  int nwg = gridDim.x;
  int wg = blockIdx.x;
  int cpx = nwg>>3;                 // all grids here are %8==0 -> bijective XCD swizzle
  wg = (wg&7)*cpx + (wg>>3);
  int brow = wg/nbn, bcol = wg%nbn;

  auto stage = [&](int buf, int kt){
    #pragma unroll
    for (int i=0;i<2;++i){
      int cb = i*256 + wid*64;      // wave-uniform chunk base
      int c  = cb + lane;
      int row = c>>2, kc = c&3;     // 4 x 16B chunks per 32-elem row
      const u16* ga = A + (size_t)(brow*128+row)*K + kt*32 + kc*8;
      __builtin_amdgcn_global_load_lds((const __attribute__((address_space(1))) u32*)ga,
          (__attribute__((address_space(3))) u32*)&lds[buf][0][cb*8], 16, 0, 0);
      const u16* gb = B + (size_t)(bcol*128+row)*K + kt*32 + kc*8;
      __builtin_amdgcn_global_load_lds((const __attribute__((address_space(1))) u32*)gb,
          (__attribute__((address_space(3))) u32*)&lds[buf][1][cb*8], 16, 0, 0);
    }
  };

  int wm = wid>>1, wn = wid&1;
  f32x4 acc[4][4] = {};
  int nkt = K>>5;
  stage(0,0);
  __syncthreads();
  for (int kt=0; kt<nkt; ++kt){
    int cur = kt&1;
    if (kt+1<nkt) stage(cur^1, kt+1);
    short8 af[4], bfr[4];
    int r = lane&15, kq = lane>>4;
    #pragma unroll
    for (int mi=0;mi<4;++mi) af[mi]  = *(const short8*)&lds[cur][0][(wm*64+mi*16+r)*32 + kq*8];
    #pragma unroll
    for (int ni=0;ni<4;++ni) bfr[ni] = *(const short8*)&lds[cur][1][(wn*64+ni*16+r)*32 + kq*8];
    #pragma unroll
    for (int mi=0;mi<4;++mi)
      #pragma unroll
      for (int ni=0;ni<4;++ni)
        acc[mi][ni] = __builtin_amdgcn_mfma_f32_16x16x32_bf16(af[mi], bfr[ni], acc[mi][ni], 0,0,0);
    __syncthreads();
  }
  int r4 = (lane>>4)*4, cc = lane&15;
  #pragma unroll
  for (int mi=0;mi<4;++mi)
    #pragma unroll
    for (int ni=0;ni<4;++ni)
      #pragma unroll
      for (int rr=0;rr<4;++rr){
        int row = brow*128 + wm*64 + mi*16 + r4 + rr;
        int col = bcol*128 + wn*64 + ni*16 + cc;
        float val = acc[mi][ni][rr];
        if (OUT_BF16) ((u16*)Cv)[(size_t)row*N+col] = f2bf(val);
        else          ((float*)Cv)[(size_t)row*N+col] = val;
      }
}

// ---------------- bucket queries by (batch, image) ----------------
__global__ void bucket_kernel(const int* __restrict__ ml32, const int* __restrict__ flag,
                              int* __restrict__ counts, int* __restrict__ lists){
  int i = blockIdx.x*256 + threadIdx.x;   // 0..16383 = b*4096+s
  int loc = flag[0] ? ml32[2*i] : ml32[i];
  int bl = (i>>12)*8 + loc;
  int pos = atomicAdd(&counts[bl], 1);
  lists[bl*4096 + pos] = i & 4095;
}

// ---------------- bucketed attention: 64 keys/query ----------------
// grid (chunk=128, head=8, b*8+loc=32), block 256 = 4 waves, 8 queries/wave.
__global__ __launch_bounds__(256) void attn_kernel(const u16* __restrict__ qb, const u16* __restrict__ kvb,
                                                   u16* __restrict__ ob, const int* __restrict__ counts,
                                                   const int* __restrict__ lists){
  int bl = blockIdx.z, h = blockIdx.y, chunk = blockIdx.x;
  int cnt = counts[bl];
  int q0 = chunk*32;
  if (q0 >= cnt) return;
  int b = bl>>3, loc = bl&7;
  int tid = threadIdx.x, lane = tid&63, wid = tid>>6;
  __shared__ float kf[64][65];
  __shared__ float vf[64][65];
  const u16* kvbase = kvb + ((size_t)(b*512 + loc*64))*1024 + h*64;
  #pragma unroll
  for (int i=0;i<2;++i){
    int e = (i*256+tid)*8;          // element 0..4095 of the 64x64 block
    int j = e>>6, d = e&63;
    short8 k8 = *(const short8*)(kvbase + (size_t)j*1024 + d);
    short8 v8 = *(const short8*)(kvbase + (size_t)j*1024 + 512 + d);
    #pragma unroll
    for (int u=0;u<8;++u){ kf[j][d+u]=bf2f(((u16*)&k8)[u]); vf[j][d+u]=bf2f(((u16*)&v8)[u]); }
  }
  __syncthreads();
  int base = q0 + wid*8;
  float qv[8]; int qi[8];
  #pragma unroll
  for (int t=0;t<8;++t){
    int p = base+t;
    if (p < cnt){ qi[t] = lists[bl*4096 + p];
                  qv[t] = bf2f(qb[((size_t)(b*4096)+qi[t])*512 + h*64 + lane]); }
    else        { qi[t] = -1; qv[t] = 0.f; }
  }
  // QK^T: lane = key j; q broadcast via readlane
  float lg[8] = {0,0,0,0,0,0,0,0};
  #pragma unroll
  for (int d=0;d<64;++d){
    float kd = kf[lane][d];
    #pragma unroll
    for (int t=0;t<8;++t){
      float qd = __int_as_float(__builtin_amdgcn_readlane(__float_as_int(qv[t]), d));
      lg[t] = fmaf(qd, kd, lg[t]);
    }
  }
  // softmax over 64 lanes (= 64 keys)
  float pr[8];
  #pragma unroll
  for (int t=0;t<8;++t){
    float l = lg[t]*0.125f;
    float m = l;
    #pragma unroll
    for (int off=32;off;off>>=1) m = fmaxf(m, __shfl_xor(m,off,64));
    float e = __expf(l-m);
    float ssum = e;
    #pragma unroll
    for (int off=32;off;off>>=1) ssum += __shfl_xor(ssum,off,64);
    pr[t] = e/ssum;
  }
  // PV: lane = out dim d; p broadcast via readlane
  float ov[8] = {0,0,0,0,0,0,0,0};
  #pragma unroll
  for (int j=0;j<64;++j){
    float vv = vf[j][lane];
    #pragma unroll
    for (int t=0;t<8;++t){
      float pj = __int_as_float(__builtin_amdgcn_readlane(__float_as_int(pr[t]), j));
      ov[t] = fmaf(pj, vv, ov[t]);
    }
  }
  #pragma unroll
  for (int t=0;t<8;++t) if (qi[t]>=0)
    ob[((size_t)(b*4096)+qi[t])*512 + h*64 + lane] = f2bf(ov[t]);
}

extern "C" void kernel_launch(void* const* d_in, const int* in_sizes, int n_in,
                              void* d_out, int out_size, void* d_ws, size_t ws_size,
                              hipStream_t stream) {
  const float* x    = (const float*)d_in[0];
  const float* ctx  = (const float*)d_in[1];
  const int*   ml   = (const int*)d_in[2];
  const float* nw   = (const float*)d_in[3];
  const float* nb   = (const float*)d_in[4];
  const float* ncw  = (const float*)d_in[5];
  const float* ncb  = (const float*)d_in[6];
  const float* Wq   = (const float*)d_in[7];
  const float* Wkv  = (const float*)d_in[8];
  const float* Wout = (const float*)d_in[9];
  float* out = (float*)d_out;
  char* ws = (char*)d_ws;
  if (ws_size < WS_NEEDED) return;   // fail loudly (output stays poisoned)

  int* flag   = (int*)(ws + OFF_FLAG);
  int* counts = (int*)(ws + OFF_COUNTS);
  int* lists  = (int*)(ws + OFF_LISTS);
  u16* xn     = (u16*)(ws + OFF_XN);
  u16* ctxn   = (u16*)(ws + OFF_CTXN);
  u16* WqT    = (u16*)(ws + OFF_WQT);
  u16* WkvT   = (u16*)(ws + OFF_WKVT);
  u16* WoutT  = (u16*)(ws + OFF_WOUTT);
  u16* qbuf   = (u16*)(ws + OFF_Q);
  u16* kvbuf  = (u16*)(ws + OFF_KV);
  u16* attn_o = (u16*)(ws + OFF_ATTN);

  prep_kernel<<<1,256,0,stream>>>(ml, flag, counts);
  ln_bf16<2048><<<16384,256,0,stream>>>(x,   nw,  nb,  xn);
  ln_bf16<1024><<<2048, 256,0,stream>>>(ctx, ncw, ncb, ctxn);
  transpose_w<<<dim3(16,64), dim3(32,8),0,stream>>>(Wq,   WqT,   2048, 512);
  transpose_w<<<dim3(32,32), dim3(32,8),0,stream>>>(Wkv,  WkvT,  1024, 1024);
  transpose_w<<<dim3(64,16), dim3(32,8),0,stream>>>(Wout, WoutT, 512,  2048);
  gemm_bt<1><<<512, 256,0,stream>>>(xn,   WqT,  qbuf,  16384, 512,  2048);
  gemm_bt<1><<<128, 256,0,stream>>>(ctxn, WkvT, kvbuf, 2048,  1024, 1024);
  bucket_kernel<<<64,256,0,stream>>>(ml, flag, counts, lists);
  attn_kernel<<<dim3(128,8,32),256,0,stream>>>(qbuf, kvbuf, attn_o, counts, lists);
  gemm_bt<0><<<2048,256,0,stream>>>(attn_o, WoutT, out, 16384, 2048, 512);
}

// Round 4
// 244.811 us; speedup vs baseline: 1.6024x; 1.6024x over previous
//
#include <hip/hip_runtime.h>

typedef unsigned short u16;
typedef unsigned int u32;
typedef __attribute__((ext_vector_type(8))) short short8;
typedef __attribute__((ext_vector_type(4))) short short4_t;
typedef __attribute__((ext_vector_type(4))) float f32x4;

__device__ __forceinline__ float bf2f(u16 u){ return __uint_as_float(((u32)u)<<16); }
__device__ __forceinline__ u16 f2bf(float f){ u32 x = __float_as_uint(f); return (u16)((x + 0x7FFFu + ((x>>16)&1u)) >> 16); }

// ---------------- workspace layout (bytes) ----------------
#define OFF_FLAG   ((size_t)0)
#define OFF_COUNTS ((size_t)256)
#define OFF_LISTS  ((size_t)4096)
#define OFF_XN     ((size_t)(1<<20))
#define OFF_CTXN   (OFF_XN    + (size_t)67108864)
#define OFF_WQT    (OFF_CTXN  + (size_t)4194304)
#define OFF_WKVT   (OFF_WQT   + (size_t)2097152)
#define OFF_WOUTT  (OFF_WKVT  + (size_t)2097152)
#define OFF_Q      (OFF_WOUTT + (size_t)2097152)
#define OFF_KV     (OFF_Q     + (size_t)16777216)
#define OFF_ATTN   (OFF_KV    + (size_t)4194304)
#define OFF_VT     (OFF_ATTN  + (size_t)16777216)
#define WS_NEEDED  (OFF_VT    + (size_t)2097152)

// ---------------- prep: detect int64 + zero bucket counts ----------------
__global__ void prep_kernel(const int* __restrict__ ml32, int* __restrict__ flag, int* __restrict__ counts){
  int t = threadIdx.x;
  if (t < 32) counts[t] = 0;
  __shared__ int nz;
  if (t == 0) nz = 0;
  __syncthreads();
  if (t < 128 && ml32[2*t+1] != 0) atomicAdd(&nz, 1);
  __syncthreads();
  if (t == 0) flag[0] = (nz == 0) ? 1 : 0;
}

// ---------------- fused LayerNorm -> bf16 ----------------
template<int D>
__global__ __launch_bounds__(256) void ln_bf16(const float* __restrict__ x, const float* __restrict__ w,
                                               const float* __restrict__ b, u16* __restrict__ out){
  constexpr int VEC = D/256;
  int row = blockIdx.x;
  const float* xr = x + (size_t)row*D;
  int tid = threadIdx.x;
  float v[VEC];
  #pragma unroll
  for (int i=0;i<VEC;i+=4){
    f32x4 f = *(const f32x4*)(xr + tid*VEC + i);
    v[i]=f[0]; v[i+1]=f[1]; v[i+2]=f[2]; v[i+3]=f[3];
  }
  float s=0.f, sq=0.f;
  #pragma unroll
  for (int i=0;i<VEC;++i){ s += v[i]; sq += v[i]*v[i]; }
  #pragma unroll
  for (int off=32;off;off>>=1){ s += __shfl_xor(s,off,64); sq += __shfl_xor(sq,off,64); }
  __shared__ float red[8];
  int lane = tid&63, wid = tid>>6;
  if (lane==0){ red[wid]=s; red[4+wid]=sq; }
  __syncthreads();
  s  = red[0]+red[1]+red[2]+red[3];
  sq = red[4]+red[5]+red[6]+red[7];
  float mu = s/(float)D;
  float var = sq/(float)D - mu*mu;
  float rs = rsqrtf(var + 1e-5f);
  u16 o[VEC];
  #pragma unroll
  for (int i=0;i<VEC;i+=4){
    f32x4 wv = *(const f32x4*)(w + tid*VEC + i);
    f32x4 bv = *(const f32x4*)(b + tid*VEC + i);
    #pragma unroll
    for (int u=0;u<4;++u) o[i+u] = f2bf((v[i+u]-mu)*rs*wv[u] + bv[u]);
  }
  if constexpr (VEC==8) *(short8*)(out + (size_t)row*D + tid*8) = *(short8*)o;
  else                  *(short4_t*)(out + (size_t)row*D + tid*4) = *(short4_t*)o;
}

// ---------------- tiled transpose f32 [K][N] -> bf16 [N][K] ----------------
__global__ __launch_bounds__(256) void transpose_w(const float* __restrict__ in, u16* __restrict__ out, int K, int N){
  __shared__ float t[32][33];
  int tx = threadIdx.x, ty = threadIdx.y;
  int n0 = blockIdx.x*32, k0 = blockIdx.y*32;
  #pragma unroll
  for (int r=0;r<32;r+=8) t[ty+r][tx] = in[(size_t)(k0+ty+r)*N + n0+tx];
  __syncthreads();
  #pragma unroll
  for (int r=0;r<32;r+=8) out[(size_t)(n0+ty+r)*K + k0+tx] = f2bf(t[tx][ty+r]);
}

// ---------------- V transpose: kv V-half [key][h*64+d] -> vt [bl][h][d][key] ----------------
__global__ __launch_bounds__(256) void transpose_v(const u16* __restrict__ kvb, u16* __restrict__ vt){
  int h = blockIdx.x, bl = blockIdx.y;
  __shared__ u16 t[64][72];
  int tid = threadIdx.x;
  const u16* src = kvb + (size_t)(bl*64)*1024 + 512 + h*64;
  #pragma unroll
  for (int i=0;i<2;++i){
    int idx = i*2048 + tid*8;
    int key = idx>>6, d = idx&63;
    *(short8*)&t[key][d] = *(const short8*)(src + (size_t)key*1024 + d);
  }
  __syncthreads();
  u16* dst = vt + (size_t)(bl*8+h)*4096;
  #pragma unroll
  for (int i=0;i<2;++i){
    int idx = i*2048 + tid*8;
    int d = idx>>6, k0 = idx&63;
    u16 tmp[8];
    #pragma unroll
    for (int u=0;u<8;++u) tmp[u] = t[k0+u][d];
    *(short8*)(dst + d*64 + k0) = *(short8*)tmp;
  }
}

// ---------------- bf16 GEMM: C[M,N] = A[M,K] * B^T  (B stored [N][K]) ----------------
// MODE: 0 = f32 out, 1 = bf16 out, 2 = bf16 out scaled by 0.125 (exact)
template<int MODE>
__global__ __launch_bounds__(256) void gemm_bt(const u16* __restrict__ A, const u16* __restrict__ B,
                                               void* __restrict__ Cv, int M, int N, int K){
  __shared__ __align__(16) u16 lds[2][2][128*32];
  int tid = threadIdx.x, lane = tid&63, wid = tid>>6;
  int nbn = N>>7;
  int nwg = gridDim.x;
  int wg = blockIdx.x;
  int cpx = nwg>>3;                 // all grids here are %8==0 -> bijective XCD swizzle
  wg = (wg&7)*cpx + (wg>>3);
  int brow = wg/nbn, bcol = wg%nbn;

  auto stage = [&](int buf, int kt){
    #pragma unroll
    for (int i=0;i<2;++i){
      int cb = i*256 + wid*64;      // wave-uniform chunk base
      int c  = cb + lane;
      int row = c>>2, kc = c&3;
      const u16* ga = A + (size_t)(brow*128+row)*K + kt*32 + kc*8;
      __builtin_amdgcn_global_load_lds((const __attribute__((address_space(1))) u32*)ga,
          (__attribute__((address_space(3))) u32*)&lds[buf][0][cb*8], 16, 0, 0);
      const u16* gb = B + (size_t)(bcol*128+row)*K + kt*32 + kc*8;
      __builtin_amdgcn_global_load_lds((const __attribute__((address_space(1))) u32*)gb,
          (__attribute__((address_space(3))) u32*)&lds[buf][1][cb*8], 16, 0, 0);
    }
  };

  int wm = wid>>1, wn = wid&1;
  f32x4 acc[4][4] = {};
  int nkt = K>>5;
  stage(0,0);
  __syncthreads();
  for (int kt=0; kt<nkt; ++kt){
    int cur = kt&1;
    if (kt+1<nkt) stage(cur^1, kt+1);
    short8 af[4], bfr[4];
    int r = lane&15, kq = lane>>4;
    #pragma unroll
    for (int mi=0;mi<4;++mi) af[mi]  = *(const short8*)&lds[cur][0][(wm*64+mi*16+r)*32 + kq*8];
    #pragma unroll
    for (int ni=0;ni<4;++ni) bfr[ni] = *(const short8*)&lds[cur][1][(wn*64+ni*16+r)*32 + kq*8];
    #pragma unroll
    for (int mi=0;mi<4;++mi)
      #pragma unroll
      for (int ni=0;ni<4;++ni)
        acc[mi][ni] = __builtin_amdgcn_mfma_f32_16x16x32_bf16(af[mi], bfr[ni], acc[mi][ni], 0,0,0);
    __syncthreads();
  }
  int r4 = (lane>>4)*4, cc = lane&15;
  #pragma unroll
  for (int mi=0;mi<4;++mi)
    #pragma unroll
    for (int ni=0;ni<4;++ni)
      #pragma unroll
      for (int rr=0;rr<4;++rr){
        int row = brow*128 + wm*64 + mi*16 + r4 + rr;
        int col = bcol*128 + wn*64 + ni*16 + cc;
        float val = acc[mi][ni][rr];
        if (MODE==2) val *= 0.125f;
        if (MODE)  ((u16*)Cv)[(size_t)row*N+col] = f2bf(val);
        else       ((float*)Cv)[(size_t)row*N+col] = val;
      }
}

// ---------------- bucket queries by (batch, image) ----------------
__global__ void bucket_kernel(const int* __restrict__ ml32, const int* __restrict__ flag,
                              int* __restrict__ counts, int* __restrict__ lists){
  int i = blockIdx.x*256 + threadIdx.x;   // 0..16383 = b*4096+s
  int loc = flag[0] ? ml32[2*i] : ml32[i];
  int bl = (i>>12)*8 + loc;
  int pos = atomicAdd(&counts[bl], 1);
  lists[bl*4096 + pos] = i & 4095;
}

// ---------------- MFMA bucketed attention ----------------
// grid (chunk<=64, headgroup=2, bucket=32), block 256 = 4 waves.
// Each wave: one head, 64 queries. Q pre-scaled by 0.125 (folded into Q-GEMM).
// QK^T: 32x mfma_16x16x32; softmax in C-layout (col=lane&15, row=(lane>>4)*4+reg);
// P -> bf16 via per-wave LDS [64][72]; PV: 32x mfma with V^T [d][key] B-frags.
__global__ __launch_bounds__(256) void attn_mfma(const u16* __restrict__ qb, const u16* __restrict__ kvb,
                                                 const u16* __restrict__ vt, u16* __restrict__ ob,
                                                 const int* __restrict__ counts, const int* __restrict__ lists){
  int bl = blockIdx.z, hg = blockIdx.y, chunk = blockIdx.x;
  int cnt = counts[bl];
  int q0 = chunk*64;
  if (q0 >= cnt) return;
  int b = bl>>3, loc = bl&7;
  int tid = threadIdx.x, lane = tid&63, wid = tid>>6;
  int h = hg*4 + wid;
  __shared__ u16 plds[4][64][72];

  int r = lane&15, g = lane>>4;

  // query indices: lane holds query (q0 + mt*16 + r)
  int qidx[4];
  #pragma unroll
  for (int mt=0;mt<4;++mt){
    int p = q0 + mt*16 + r;
    qidx[mt] = (p < cnt) ? lists[bl*4096 + p] : -1;
  }

  // Q fragments [mt][kstep]
  short8 qf[4][2];
  #pragma unroll
  for (int mt=0;mt<4;++mt){
    int qi = qidx[mt] < 0 ? 0 : qidx[mt];
    const u16* qrow = qb + ((size_t)(b*4096) + qi)*512 + h*64;
    qf[mt][0] = *(const short8*)(qrow + g*8);
    qf[mt][1] = *(const short8*)(qrow + 32 + g*8);
  }
  // K fragments [nt][kstep]: key = nt*16 + r
  const u16* kbase = kvb + (size_t)(b*512 + loc*64)*1024 + h*64;
  short8 kfr[4][2];
  #pragma unroll
  for (int nt=0;nt<4;++nt){
    const u16* krow = kbase + (size_t)(nt*16 + r)*1024;
    kfr[nt][0] = *(const short8*)(krow + g*8);
    kfr[nt][1] = *(const short8*)(krow + 32 + g*8);
  }

  f32x4 acc[4][4] = {};
  #pragma unroll
  for (int mt=0;mt<4;++mt)
    #pragma unroll
    for (int nt=0;nt<4;++nt){
      acc[mt][nt] = __builtin_amdgcn_mfma_f32_16x16x32_bf16(qf[mt][0], kfr[nt][0], acc[mt][nt], 0,0,0);
      acc[mt][nt] = __builtin_amdgcn_mfma_f32_16x16x32_bf16(qf[mt][1], kfr[nt][1], acc[mt][nt], 0,0,0);
    }

  // softmax per query row; scores for row (mt*16 + g*4 + rr): acc[mt][nt][rr] over nt and 16 lanes (r)
  #pragma unroll
  for (int mt=0;mt<4;++mt){
    #pragma unroll
    for (int rr=0;rr<4;++rr){
      float m = fmaxf(fmaxf(acc[mt][0][rr], acc[mt][1][rr]), fmaxf(acc[mt][2][rr], acc[mt][3][rr]));
      #pragma unroll
      for (int off=1;off<16;off<<=1) m = fmaxf(m, __shfl_xor(m, off));
      float e0 = __expf(acc[mt][0][rr]-m), e1 = __expf(acc[mt][1][rr]-m);
      float e2 = __expf(acc[mt][2][rr]-m), e3 = __expf(acc[mt][3][rr]-m);
      float sum = (e0+e1)+(e2+e3);
      #pragma unroll
      for (int off=1;off<16;off<<=1) sum += __shfl_xor(sum, off);
      float rs = 1.0f/sum;
      int row = mt*16 + g*4 + rr;
      plds[wid][row][ 0 + r] = f2bf(e0*rs);
      plds[wid][row][16 + r] = f2bf(e1*rs);
      plds[wid][row][32 + r] = f2bf(e2*rs);
      plds[wid][row][48 + r] = f2bf(e3*rs);
    }
  }

  // V fragments from vt [bl][h][d][key]: n-col d = nt*16 + r, k = keys ks*32 + g*8
  const u16* vbase = vt + (size_t)(bl*8 + h)*4096;
  short8 vf[2][4];
  #pragma unroll
  for (int nt=0;nt<4;++nt){
    const u16* vrow = vbase + (size_t)(nt*16 + r)*64;
    vf[0][nt] = *(const short8*)(vrow + g*8);
    vf[1][nt] = *(const short8*)(vrow + 32 + g*8);
  }

  // PV: reuse acc as output accumulator
  #pragma unroll
  for (int mt=0;mt<4;++mt)
    #pragma unroll
    for (int nt=0;nt<4;++nt)
      acc[mt][nt] = (f32x4){0.f,0.f,0.f,0.f};
  #pragma unroll
  for (int mt=0;mt<4;++mt){
    short8 pa0 = *(const short8*)&plds[wid][mt*16 + r][g*8];
    short8 pa1 = *(const short8*)&plds[wid][mt*16 + r][32 + g*8];
    #pragma unroll
    for (int nt=0;nt<4;++nt){
      acc[mt][nt] = __builtin_amdgcn_mfma_f32_16x16x32_bf16(pa0, vf[0][nt], acc[mt][nt], 0,0,0);
      acc[mt][nt] = __builtin_amdgcn_mfma_f32_16x16x32_bf16(pa1, vf[1][nt], acc[mt][nt], 0,0,0);
    }
  }

  // epilogue: C layout col d = nt*16 + r, row query = mt*16 + g*4 + rr
  #pragma unroll
  for (int mt=0;mt<4;++mt){
    #pragma unroll
    for (int rr=0;rr<4;++rr){
      int qrow = __shfl(qidx[mt], g*4 + rr, 16);
      if (qrow >= 0){
        u16* orow = ob + ((size_t)(b*4096) + qrow)*512 + h*64;
        #pragma unroll
        for (int nt=0;nt<4;++nt) orow[nt*16 + r] = f2bf(acc[mt][nt][rr]);
      }
    }
  }
}

extern "C" void kernel_launch(void* const* d_in, const int* in_sizes, int n_in,
                              void* d_out, int out_size, void* d_ws, size_t ws_size,
                              hipStream_t stream) {
  const float* x    = (const float*)d_in[0];
  const float* ctx  = (const float*)d_in[1];
  const int*   ml   = (const int*)d_in[2];
  const float* nw   = (const float*)d_in[3];
  const float* nb   = (const float*)d_in[4];
  const float* ncw  = (const float*)d_in[5];
  const float* ncb  = (const float*)d_in[6];
  const float* Wq   = (const float*)d_in[7];
  const float* Wkv  = (const float*)d_in[8];
  const float* Wout = (const float*)d_in[9];
  float* out = (float*)d_out;
  char* ws = (char*)d_ws;
  if (ws_size < WS_NEEDED) return;   // fail loudly (output stays poisoned)

  int* flag   = (int*)(ws + OFF_FLAG);
  int* counts = (int*)(ws + OFF_COUNTS);
  int* lists  = (int*)(ws + OFF_LISTS);
  u16* xn     = (u16*)(ws + OFF_XN);
  u16* ctxn   = (u16*)(ws + OFF_CTXN);
  u16* WqT    = (u16*)(ws + OFF_WQT);
  u16* WkvT   = (u16*)(ws + OFF_WKVT);
  u16* WoutT  = (u16*)(ws + OFF_WOUTT);
  u16* qbuf   = (u16*)(ws + OFF_Q);
  u16* kvbuf  = (u16*)(ws + OFF_KV);
  u16* attn_o = (u16*)(ws + OFF_ATTN);
  u16* vtbuf  = (u16*)(ws + OFF_VT);

  prep_kernel<<<1,256,0,stream>>>(ml, flag, counts);
  ln_bf16<2048><<<16384,256,0,stream>>>(x,   nw,  nb,  xn);
  ln_bf16<1024><<<2048, 256,0,stream>>>(ctx, ncw, ncb, ctxn);
  transpose_w<<<dim3(16,64), dim3(32,8),0,stream>>>(Wq,   WqT,   2048, 512);
  transpose_w<<<dim3(32,32), dim3(32,8),0,stream>>>(Wkv,  WkvT,  1024, 1024);
  transpose_w<<<dim3(64,16), dim3(32,8),0,stream>>>(Wout, WoutT, 512,  2048);
  gemm_bt<2><<<512, 256,0,stream>>>(xn,   WqT,  qbuf,  16384, 512,  2048);  // Q, pre-scaled 0.125
  gemm_bt<1><<<128, 256,0,stream>>>(ctxn, WkvT, kvbuf, 2048,  1024, 1024);
  transpose_v<<<dim3(8,32),256,0,stream>>>(kvbuf, vtbuf);
  bucket_kernel<<<64,256,0,stream>>>(ml, flag, counts, lists);
  attn_mfma<<<dim3(64,2,32),256,0,stream>>>(qbuf, kvbuf, vtbuf, attn_o, counts, lists);
  gemm_bt<0><<<2048,256,0,stream>>>(attn_o, WoutT, out, 16384, 2048, 512);
}

// Round 5
// 237.399 us; speedup vs baseline: 1.6525x; 1.0312x over previous
//
#include <hip/hip_runtime.h>

typedef unsigned short u16;
typedef unsigned int u32;
typedef __attribute__((ext_vector_type(8))) short short8;
typedef __attribute__((ext_vector_type(4))) short short4_t;
typedef __attribute__((ext_vector_type(4))) float f32x4;

__device__ __forceinline__ float bf2f(u16 u){ return __uint_as_float(((u32)u)<<16); }
__device__ __forceinline__ u16 f2bf(float f){ u32 x = __float_as_uint(f); return (u16)((x + 0x7FFFu + ((x>>16)&1u)) >> 16); }

// ---------------- workspace layout (bytes) ----------------
#define OFF_FLAG   ((size_t)0)
#define OFF_COUNTS ((size_t)256)
#define OFF_LISTS  ((size_t)4096)
#define OFF_XN     ((size_t)(1<<20))
#define OFF_CTXN   (OFF_XN    + (size_t)67108864)
#define OFF_WQT    (OFF_CTXN  + (size_t)4194304)
#define OFF_WKVT   (OFF_WQT   + (size_t)2097152)
#define OFF_WOUTT  (OFF_WKVT  + (size_t)2097152)
#define OFF_Q      (OFF_WOUTT + (size_t)2097152)
#define OFF_KV     (OFF_Q     + (size_t)16777216)
#define OFF_ATTN   (OFF_KV    + (size_t)4194304)
#define OFF_VT     (OFF_ATTN  + (size_t)16777216)
#define WS_NEEDED  (OFF_VT    + (size_t)2097152)

// ---------------- prep: detect int64 + zero bucket counts ----------------
__global__ void prep_kernel(const int* __restrict__ ml32, int* __restrict__ flag, int* __restrict__ counts){
  int t = threadIdx.x;
  if (t < 32) counts[t] = 0;
  __shared__ int nz;
  if (t == 0) nz = 0;
  __syncthreads();
  if (t < 128 && ml32[2*t+1] != 0) atomicAdd(&nz, 1);
  __syncthreads();
  if (t == 0) flag[0] = (nz == 0) ? 1 : 0;
}

// ---------------- fused LayerNorm -> bf16 ----------------
template<int D>
__global__ __launch_bounds__(256) void ln_bf16(const float* __restrict__ x, const float* __restrict__ w,
                                               const float* __restrict__ b, u16* __restrict__ out){
  constexpr int VEC = D/256;
  int row = blockIdx.x;
  const float* xr = x + (size_t)row*D;
  int tid = threadIdx.x;
  float v[VEC];
  #pragma unroll
  for (int i=0;i<VEC;i+=4){
    f32x4 f = *(const f32x4*)(xr + tid*VEC + i);
    v[i]=f[0]; v[i+1]=f[1]; v[i+2]=f[2]; v[i+3]=f[3];
  }
  float s=0.f, sq=0.f;
  #pragma unroll
  for (int i=0;i<VEC;++i){ s += v[i]; sq += v[i]*v[i]; }
  #pragma unroll
  for (int off=32;off;off>>=1){ s += __shfl_xor(s,off,64); sq += __shfl_xor(sq,off,64); }
  __shared__ float red[8];
  int lane = tid&63, wid = tid>>6;
  if (lane==0){ red[wid]=s; red[4+wid]=sq; }
  __syncthreads();
  s  = red[0]+red[1]+red[2]+red[3];
  sq = red[4]+red[5]+red[6]+red[7];
  float mu = s/(float)D;
  float var = sq/(float)D - mu*mu;
  float rs = rsqrtf(var + 1e-5f);
  u16 o[VEC];
  #pragma unroll
  for (int i=0;i<VEC;i+=4){
    f32x4 wv = *(const f32x4*)(w + tid*VEC + i);
    f32x4 bv = *(const f32x4*)(b + tid*VEC + i);
    #pragma unroll
    for (int u=0;u<4;++u) o[i+u] = f2bf((v[i+u]-mu)*rs*wv[u] + bv[u]);
  }
  if constexpr (VEC==8) *(short8*)(out + (size_t)row*D + tid*8) = *(short8*)o;
  else                  *(short4_t*)(out + (size_t)row*D + tid*4) = *(short4_t*)o;
}

// ---------------- tiled transpose f32 [K][N] -> bf16 [N][K] ----------------
__global__ __launch_bounds__(256) void transpose_w(const float* __restrict__ in, u16* __restrict__ out, int K, int N){
  __shared__ float t[32][33];
  int tx = threadIdx.x, ty = threadIdx.y;
  int n0 = blockIdx.x*32, k0 = blockIdx.y*32;
  #pragma unroll
  for (int r=0;r<32;r+=8) t[ty+r][tx] = in[(size_t)(k0+ty+r)*N + n0+tx];
  __syncthreads();
  #pragma unroll
  for (int r=0;r<32;r+=8) out[(size_t)(n0+ty+r)*K + k0+tx] = f2bf(t[tx][ty+r]);
}

// ---------------- V transpose: kv V-half [key][h*64+d] -> vt [bl][h][d][key] ----------------
__global__ __launch_bounds__(256) void transpose_v(const u16* __restrict__ kvb, u16* __restrict__ vt){
  int h = blockIdx.x, bl = blockIdx.y;
  __shared__ u16 t[64][72];
  int tid = threadIdx.x;
  const u16* src = kvb + (size_t)(bl*64)*1024 + 512 + h*64;
  #pragma unroll
  for (int i=0;i<2;++i){
    int idx = i*2048 + tid*8;
    int key = idx>>6, d = idx&63;
    *(short8*)&t[key][d] = *(const short8*)(src + (size_t)key*1024 + d);
  }
  __syncthreads();
  u16* dst = vt + (size_t)(bl*8+h)*4096;
  #pragma unroll
  for (int i=0;i<2;++i){
    int idx = i*2048 + tid*8;
    int d = idx>>6, k0 = idx&63;
    u16 tmp[8];
    #pragma unroll
    for (int u=0;u<8;++u) tmp[u] = t[k0+u][d];
    *(short8*)(dst + d*64 + k0) = *(short8*)tmp;
  }
}

// ---------------- bf16 GEMM: C[M,N] = A[M,K] * B^T  (B stored [N][K]) ----------------
// MODE: 0 = f32 out, 1 = bf16 out, 2 = bf16 out scaled by 0.125 (exact)
template<int MODE>
__global__ __launch_bounds__(256) void gemm_bt(const u16* __restrict__ A, const u16* __restrict__ B,
                                               void* __restrict__ Cv, int M, int N, int K){
  __shared__ __align__(16) u16 lds[2][2][128*32];
  int tid = threadIdx.x, lane = tid&63, wid = tid>>6;
  int nbn = N>>7;
  int nwg = gridDim.x;
  int wg = blockIdx.x;
  int cpx = nwg>>3;                 // all grids here are %8==0 -> bijective XCD swizzle
  wg = (wg&7)*cpx + (wg>>3);
  int brow = wg/nbn, bcol = wg%nbn;

  auto stage = [&](int buf, int kt){
    #pragma unroll
    for (int i=0;i<2;++i){
      int cb = i*256 + wid*64;      // wave-uniform chunk base
      int c  = cb + lane;
      int row = c>>2, kc = c&3;
      const u16* ga = A + (size_t)(brow*128+row)*K + kt*32 + kc*8;
      __builtin_amdgcn_global_load_lds((const __attribute__((address_space(1))) u32*)ga,
          (__attribute__((address_space(3))) u32*)&lds[buf][0][cb*8], 16, 0, 0);
      const u16* gb = B + (size_t)(bcol*128+row)*K + kt*32 + kc*8;
      __builtin_amdgcn_global_load_lds((const __attribute__((address_space(1))) u32*)gb,
          (__attribute__((address_space(3))) u32*)&lds[buf][1][cb*8], 16, 0, 0);
    }
  };

  int wm = wid>>1, wn = wid&1;
  f32x4 acc[4][4] = {};
  int nkt = K>>5;
  stage(0,0);
  __syncthreads();
  for (int kt=0; kt<nkt; ++kt){
    int cur = kt&1;
    if (kt+1<nkt) stage(cur^1, kt+1);
    short8 af[4], bfr[4];
    int r = lane&15, kq = lane>>4;
    #pragma unroll
    for (int mi=0;mi<4;++mi) af[mi]  = *(const short8*)&lds[cur][0][(wm*64+mi*16+r)*32 + kq*8];
    #pragma unroll
    for (int ni=0;ni<4;++ni) bfr[ni] = *(const short8*)&lds[cur][1][(wn*64+ni*16+r)*32 + kq*8];
    #pragma unroll
    for (int mi=0;mi<4;++mi)
      #pragma unroll
      for (int ni=0;ni<4;++ni)
        acc[mi][ni] = __builtin_amdgcn_mfma_f32_16x16x32_bf16(af[mi], bfr[ni], acc[mi][ni], 0,0,0);
    __syncthreads();
  }
  int r4 = (lane>>4)*4, cc = lane&15;
  #pragma unroll
  for (int mi=0;mi<4;++mi)
    #pragma unroll
    for (int ni=0;ni<4;++ni)
      #pragma unroll
      for (int rr=0;rr<4;++rr){
        int row = brow*128 + wm*64 + mi*16 + r4 + rr;
        int col = bcol*128 + wn*64 + ni*16 + cc;
        float val = acc[mi][ni][rr];
        if (MODE==2) val *= 0.125f;
        if (MODE)  ((u16*)Cv)[(size_t)row*N+col] = f2bf(val);
        else       ((float*)Cv)[(size_t)row*N+col] = val;
      }
}

// ---------------- bucket queries by (batch, image) ----------------
__global__ void bucket_kernel(const int* __restrict__ ml32, const int* __restrict__ flag,
                              int* __restrict__ counts, int* __restrict__ lists){
  int i = blockIdx.x*256 + threadIdx.x;   // 0..16383 = b*4096+s
  int loc = flag[0] ? ml32[2*i] : ml32[i];
  int bl = (i>>12)*8 + loc;
  int pos = atomicAdd(&counts[bl], 1);
  lists[bl*4096 + pos] = i & 4095;
}

// ---------------- MFMA bucketed attention, v2 ----------------
// grid (chunk=128, bucket=32), block 512 = 8 waves = 8 heads; 32 queries/block.
// Q rows gathered ONCE per block into LDS with row-contiguous coalesced copies
// (wave-per-row); output staged in the same buffer and scattered the same way.
// QK^T: 16 mfma/wave; softmax in C-layout; P via per-wave LDS [32][72];
// PV: 16 mfma/wave with V^T [d][key] B-frags.  Q pre-scaled by 0.125.
__global__ __launch_bounds__(512) void attn_mfma2(const u16* __restrict__ qb, const u16* __restrict__ kvb,
                                                  const u16* __restrict__ vt, u16* __restrict__ ob,
                                                  const int* __restrict__ counts, const int* __restrict__ lists){
  int bl = blockIdx.y, chunk = blockIdx.x;
  int cnt = counts[bl];
  int q0 = chunk*32;
  if (q0 >= cnt) return;
  int b = bl>>3, loc = bl&7;
  int tid = threadIdx.x, lane = tid&63, h = tid>>6;   // wave id == head
  __shared__ u16 qs[32][520];      // gathered Q rows (all heads); reused for O staging
  __shared__ u16 plds[8][32][72];  // per-wave P tile
  __shared__ int qi[32];

  if (tid < 32){
    int p = q0 + tid;
    qi[tid] = (p < cnt) ? lists[bl*4096 + p] : -1;
  }
  __syncthreads();

  // ---- coalesced gather: each wave copies one full 1KB q-row per pass ----
  const u16* qbase = qb + (size_t)(b*4096)*512;
  #pragma unroll
  for (int p=0;p<4;++p){
    int c = p*512 + tid;           // 2048 chunks of 16B: row=c>>6, chunk-in-row=c&63
    int row = c>>6, cc = c&63;
    int qq = qi[row];
    if (qq >= 0)
      *(short8*)&qs[row][cc*8] = *(const short8*)(qbase + (size_t)qq*512 + cc*8);
  }
  __syncthreads();

  int r = lane&15, g = lane>>4;

  // A-frags (Q) from LDS
  short8 qf[2][2];
  #pragma unroll
  for (int mt=0;mt<2;++mt){
    qf[mt][0] = *(const short8*)&qs[mt*16+r][h*64 + g*8];
    qf[mt][1] = *(const short8*)&qs[mt*16+r][h*64 + 32 + g*8];
  }
  __syncthreads();   // all qs reads done before O overwrites it

  // K fragments from global (L2/L3-resident): key = nt*16 + r
  const u16* kbase = kvb + (size_t)(b*512 + loc*64)*1024 + h*64;
  short8 kfr[4][2];
  #pragma unroll
  for (int nt=0;nt<4;++nt){
    const u16* krow = kbase + (size_t)(nt*16 + r)*1024;
    kfr[nt][0] = *(const short8*)(krow + g*8);
    kfr[nt][1] = *(const short8*)(krow + 32 + g*8);
  }

  // QK^T
  f32x4 acc[2][4] = {};
  #pragma unroll
  for (int mt=0;mt<2;++mt)
    #pragma unroll
    for (int nt=0;nt<4;++nt){
      acc[mt][nt] = __builtin_amdgcn_mfma_f32_16x16x32_bf16(qf[mt][0], kfr[nt][0], acc[mt][nt], 0,0,0);
      acc[mt][nt] = __builtin_amdgcn_mfma_f32_16x16x32_bf16(qf[mt][1], kfr[nt][1], acc[mt][nt], 0,0,0);
    }

  // softmax per query row (row = mt*16 + g*4 + rr; 16 lanes r hold 4 key-tiles)
  #pragma unroll
  for (int mt=0;mt<2;++mt){
    #pragma unroll
    for (int rr=0;rr<4;++rr){
      float m = fmaxf(fmaxf(acc[mt][0][rr], acc[mt][1][rr]), fmaxf(acc[mt][2][rr], acc[mt][3][rr]));
      #pragma unroll
      for (int off=1;off<16;off<<=1) m = fmaxf(m, __shfl_xor(m, off));
      float e0 = __expf(acc[mt][0][rr]-m), e1 = __expf(acc[mt][1][rr]-m);
      float e2 = __expf(acc[mt][2][rr]-m), e3 = __expf(acc[mt][3][rr]-m);
      float sum = (e0+e1)+(e2+e3);
      #pragma unroll
      for (int off=1;off<16;off<<=1) sum += __shfl_xor(sum, off);
      float rs = 1.0f/sum;
      int row = mt*16 + g*4 + rr;
      plds[h][row][ 0 + r] = f2bf(e0*rs);
      plds[h][row][16 + r] = f2bf(e1*rs);
      plds[h][row][32 + r] = f2bf(e2*rs);
      plds[h][row][48 + r] = f2bf(e3*rs);
    }
  }

  // V fragments from vt [bl][h][d][key]
  const u16* vbase = vt + (size_t)(bl*8 + h)*4096;
  short8 vf[2][4];
  #pragma unroll
  for (int nt=0;nt<4;++nt){
    const u16* vrow = vbase + (size_t)(nt*16 + r)*64;
    vf[0][nt] = *(const short8*)(vrow + g*8);
    vf[1][nt] = *(const short8*)(vrow + 32 + g*8);
  }

  // PV
  f32x4 oacc[2][4] = {};
  #pragma unroll
  for (int mt=0;mt<2;++mt){
    short8 pa0 = *(const short8*)&plds[h][mt*16 + r][g*8];
    short8 pa1 = *(const short8*)&plds[h][mt*16 + r][32 + g*8];
    #pragma unroll
    for (int nt=0;nt<4;++nt){
      oacc[mt][nt] = __builtin_amdgcn_mfma_f32_16x16x32_bf16(pa0, vf[0][nt], oacc[mt][nt], 0,0,0);
      oacc[mt][nt] = __builtin_amdgcn_mfma_f32_16x16x32_bf16(pa1, vf[1][nt], oacc[mt][nt], 0,0,0);
    }
  }

  // stage O into qs (C layout: col d = nt*16 + r, row = mt*16 + g*4 + rr)
  #pragma unroll
  for (int mt=0;mt<2;++mt)
    #pragma unroll
    for (int rr=0;rr<4;++rr){
      int row = mt*16 + g*4 + rr;
      #pragma unroll
      for (int nt=0;nt<4;++nt)
        qs[row][h*64 + nt*16 + r] = f2bf(oacc[mt][nt][rr]);
    }
  __syncthreads();

  // ---- coalesced scatter: wave-per-row, contiguous 1KB per row ----
  u16* obase = ob + (size_t)(b*4096)*512;
  #pragma unroll
  for (int p=0;p<4;++p){
    int c = p*512 + tid;
    int row = c>>6, cc = c&63;
    int qq = qi[row];
    if (qq >= 0)
      *(short8*)(obase + (size_t)qq*512 + cc*8) = *(const short8*)&qs[row][cc*8];
  }
}

extern "C" void kernel_launch(void* const* d_in, const int* in_sizes, int n_in,
                              void* d_out, int out_size, void* d_ws, size_t ws_size,
                              hipStream_t stream) {
  const float* x    = (const float*)d_in[0];
  const float* ctx  = (const float*)d_in[1];
  const int*   ml   = (const int*)d_in[2];
  const float* nw   = (const float*)d_in[3];
  const float* nb   = (const float*)d_in[4];
  const float* ncw  = (const float*)d_in[5];
  const float* ncb  = (const float*)d_in[6];
  const float* Wq   = (const float*)d_in[7];
  const float* Wkv  = (const float*)d_in[8];
  const float* Wout = (const float*)d_in[9];
  float* out = (float*)d_out;
  char* ws = (char*)d_ws;
  if (ws_size < WS_NEEDED) return;   // fail loudly (output stays poisoned)

  int* flag   = (int*)(ws + OFF_FLAG);
  int* counts = (int*)(ws + OFF_COUNTS);
  int* lists  = (int*)(ws + OFF_LISTS);
  u16* xn     = (u16*)(ws + OFF_XN);
  u16* ctxn   = (u16*)(ws + OFF_CTXN);
  u16* WqT    = (u16*)(ws + OFF_WQT);
  u16* WkvT   = (u16*)(ws + OFF_WKVT);
  u16* WoutT  = (u16*)(ws + OFF_WOUTT);
  u16* qbuf   = (u16*)(ws + OFF_Q);
  u16* kvbuf  = (u16*)(ws + OFF_KV);
  u16* attn_o = (u16*)(ws + OFF_ATTN);
  u16* vtbuf  = (u16*)(ws + OFF_VT);

  prep_kernel<<<1,256,0,stream>>>(ml, flag, counts);
  ln_bf16<2048><<<16384,256,0,stream>>>(x,   nw,  nb,  xn);
  ln_bf16<1024><<<2048, 256,0,stream>>>(ctx, ncw, ncb, ctxn);
  transpose_w<<<dim3(16,64), dim3(32,8),0,stream>>>(Wq,   WqT,   2048, 512);
  transpose_w<<<dim3(32,32), dim3(32,8),0,stream>>>(Wkv,  WkvT,  1024, 1024);
  transpose_w<<<dim3(64,16), dim3(32,8),0,stream>>>(Wout, WoutT, 512,  2048);
  gemm_bt<2><<<512, 256,0,stream>>>(xn,   WqT,  qbuf,  16384, 512,  2048);  // Q, pre-scaled 0.125
  gemm_bt<1><<<128, 256,0,stream>>>(ctxn, WkvT, kvbuf, 2048,  1024, 1024);
  transpose_v<<<dim3(8,32),256,0,stream>>>(kvbuf, vtbuf);
  bucket_kernel<<<64,256,0,stream>>>(ml, flag, counts, lists);
  attn_mfma2<<<dim3(128,32),512,0,stream>>>(qbuf, kvbuf, vtbuf, attn_o, counts, lists);
  gemm_bt<0><<<2048,256,0,stream>>>(attn_o, WoutT, out, 16384, 2048, 512);
}